// Round 3
// baseline (320.204 us; speedup 1.0000x reference)
//
#include <hip/hip_runtime.h>
#include <stdint.h>
#include <stddef.h>

#define NN 8192
#define DD 256
#define HH 128

typedef short bf16x8  __attribute__((ext_vector_type(8)));
typedef float f32x4   __attribute__((ext_vector_type(4)));
typedef float f32x16  __attribute__((ext_vector_type(16)));
typedef int   i32x4   __attribute__((ext_vector_type(4)));

// f32 -> bf16 RNE
static __device__ __forceinline__ short f2bf(float x){
  unsigned u = __float_as_uint(x);
  u = (u + 0x7FFFu + ((u >> 16) & 1u)) >> 16;
  return (short)(unsigned short)u;
}
static __device__ __forceinline__ bf16x8 cvt8(const float* p){
  f32x4 a = *(const f32x4*)p;
  f32x4 b = *(const f32x4*)(p + 4);
  bf16x8 o;
  o[0]=f2bf(a[0]); o[1]=f2bf(a[1]); o[2]=f2bf(a[2]); o[3]=f2bf(a[3]);
  o[4]=f2bf(b[0]); o[5]=f2bf(b[1]); o[6]=f2bf(b[2]); o[7]=f2bf(b[3]);
  return o;
}
static __device__ __forceinline__ bf16x8 ld16(const void* p){
  i32x4 v = *(const i32x4*)p;
  return __builtin_bit_cast(bf16x8, v);
}
// packed f32 pair -> bf16x2 in one VALU op (gfx950)
static __device__ __forceinline__ unsigned cvtpk(float lo, float hi){
  unsigned r;
  asm("v_cvt_pk_bf16_f32 %0, %1, %2" : "=v"(r) : "v"(lo), "v"(hi));
  return r;
}
static __device__ __forceinline__ bf16x8 mk8(unsigned a, unsigned b, unsigned c, unsigned d){
  i32x4 t; t[0]=(int)a; t[1]=(int)b; t[2]=(int)c; t[3]=(int)d;
  return __builtin_bit_cast(bf16x8, t);
}
static __device__ __forceinline__ void gl_lds16(const void* g, void* l){
  __builtin_amdgcn_global_load_lds((const __attribute__((address_space(1))) void*)g,
                                   (__attribute__((address_space(3))) void*)l, 16, 0, 0);
}

// ---------- features [N][D] f32 -> featT [D][N] bf16, PRE-SWIZZLED ----------
// Within each 128-j window (256B LDS row), 16B unit u stored at u ^ (d&15).
// k_attn stages rows linearly with global_load_lds and applies the XOR on read.
__global__ __launch_bounds__(256) void k_transpose(const float* __restrict__ f,
                                                   unsigned short* __restrict__ ft){
  __shared__ unsigned short tile[64][65];
  int t  = threadIdx.x;
  int i0 = blockIdx.x * 64, d0 = blockIdx.y * 64;
  int r0 = t >> 6, c = t & 63;
  for (int it = 0; it < 16; ++it){
    int r = r0 + it * 4;
    tile[c][r] = (unsigned short)f2bf(f[(size_t)(i0 + r) * DD + d0 + c]);
  }
  __syncthreads();
  int jlog = i0 + c;
  for (int it = 0; it < 16; ++it){
    int rr = r0 + it * 4;
    int d  = d0 + rr;
    int jp = (jlog & ~127) | ((((jlog >> 3) ^ d) & 15) << 3) | (jlog & 7);
    ft[(size_t)d * NN + jp] = tile[rr][c];
  }
}

// ---------- projections: Qn/Kn = cos-normalized (features @ W^T), bf16 ----------
__global__ __launch_bounds__(256) void k_proj(const float* __restrict__ f,
                                              const float* __restrict__ Wq,
                                              const float* __restrict__ Wk,
                                              unsigned short* __restrict__ Qn,
                                              unsigned short* __restrict__ Kn){
  int t = threadIdx.x, wave = t >> 6, l = t & 63;
  int i0 = blockIdx.x * 64 + wave * 16;
  int lr = l & 15, lk = l >> 4;
  bf16x8 ka[8];
  for (int ks = 0; ks < 8; ++ks)
    ka[ks] = cvt8(f + (size_t)(i0 + lr) * DD + ks * 32 + lk * 8);
  for (int pj = 0; pj < 2; ++pj){
    const float* W = pj ? Wk : Wq;
    unsigned short* out = pj ? Kn : Qn;
    f32x4 acc[8];
    for (int n = 0; n < 8; ++n) acc[n] = (f32x4){0.f,0.f,0.f,0.f};
    for (int ks = 0; ks < 8; ++ks)
      for (int n = 0; n < 8; ++n){
        bf16x8 bb = cvt8(W + (size_t)(n * 16 + lr) * DD + ks * 32 + lk * 8);
        acc[n] = __builtin_amdgcn_mfma_f32_16x16x32_bf16(ka[ks], bb, acc[n], 0, 0, 0);
      }
    for (int r = 0; r < 4; ++r){
      float n2 = 0.f;
      for (int n = 0; n < 8; ++n){ float v = acc[n][r]; n2 += v * v; }
      n2 += __shfl_xor(n2, 1); n2 += __shfl_xor(n2, 2);
      n2 += __shfl_xor(n2, 4); n2 += __shfl_xor(n2, 8);
      float s = 1.f / fmaxf(sqrtf(n2), 1e-4f);
      int row = i0 + lk * 4 + r;
      for (int n = 0; n < 8; ++n)
        out[(size_t)row * HH + n * 16 + lr] = (unsigned short)f2bf(acc[n][r] * s);
    }
  }
}

// ---------- adj (256MB int) -> bitmask (8MB), dense stream at HBM BW ----------
__global__ __launch_bounds__(256) void k_pack(const int* __restrict__ adj,
                                              unsigned* __restrict__ bits){
  int wave = threadIdx.x >> 6, l = threadIdx.x & 63;
  int gw   = blockIdx.x * 4 + wave;       // 16384 waves
  int row  = gw >> 1, half = gw & 1;
  const int* ap = adj + (size_t)row * NN + half * 4096 + l;
  unsigned long long* bp =
      (unsigned long long*)(bits + (size_t)row * 256 + half * 128);
  for (int c = 0; c < 64; ++c){
    int v = __builtin_nontemporal_load(ap + c * 64);
    unsigned long long m = __ballot(v > 0);
    if (l == 0) bp[c] = m;
  }
}

// ---------- fused masked-softmax attention (v3) ----------
// 4 waves = ig(2: 32 i-rows) x jg(2: 64-j half). BM=64, jT=128, 4 j-splits.
// Swapped QK^T (32x32x16): lane owns i=l&31 col -> P stays in-register;
// cvt_pk + shfl_xor(32) builds PV A-frags; only ft staged in LDS (swizzled).
__global__ __launch_bounds__(256, 2) void k_attn(
      const unsigned* __restrict__ bits,
      const unsigned short* __restrict__ Qn, const unsigned short* __restrict__ Kn,
      const unsigned short* __restrict__ ft,
      float* __restrict__ num_p, float* __restrict__ den_p){
  __shared__ __attribute__((aligned(256))) char smem[65792]; // 64KB ft + 256B den
  int t = threadIdx.x, wave = t >> 6, l = t & 63;
  int ig = wave >> 1, jg = wave & 1;
  int lc = l & 31, h = l >> 5;
  int ib = blockIdx.x >> 2, js = blockIdx.x & 3;
  int i0 = ib * 64;
  int jbase = js * 2048;
  int irow = i0 + ig * 32 + lc;

  // Kn B-frags: lane holds Kn[i=irow][k=16*hs + 8*h + e]
  bf16x8 kb[8];
  {
    const unsigned short* kp = Kn + (size_t)irow * HH + h * 8;
    #pragma unroll
    for (int hs = 0; hs < 8; ++hs) kb[hs] = ld16(kp + hs * 16);
  }
  f32x16 pv[8];
  #pragma unroll
  for (int dt = 0; dt < 8; ++dt)
    #pragma unroll
    for (int e = 0; e < 16; ++e) pv[dt][e] = 0.f;
  float dacc = 0.f;

  // stage ft slab [256 d][128 j] = 64KB: linear copy of pre-swizzled global
  auto stage = [&](int j0){
    #pragma unroll
    for (int q = 0; q < 16; ++q){
      int d = q * 16 + wave * 4 + (l >> 4);
      const unsigned short* src = ft + (size_t)d * NN + j0 + (l & 15) * 8;
      gl_lds16(src, smem + q * 4096 + wave * 1024);
    }
  };

  stage(jbase);
  for (int s = 0; s < 16; ++s){
    int j0 = jbase + s * 128;
    int jw = j0 + jg * 64;
    unsigned bw0 = bits[(size_t)irow * 256 + (jw >> 5)];
    unsigned bw1 = bits[(size_t)irow * 256 + (jw >> 5) + 1];

    // QK^T (swapped): st[jt][r] = S[irow][jw + jt*32 + j'], j'=(r&3)+8*(r>>2)+4h
    f32x16 st[2];
    #pragma unroll
    for (int jt = 0; jt < 2; ++jt)
      #pragma unroll
      for (int e = 0; e < 16; ++e) st[jt][e] = 0.f;
    #pragma unroll
    for (int jt = 0; jt < 2; ++jt){
      const unsigned short* qp = Qn + (size_t)(jw + jt * 32 + lc) * HH + h * 8;
      #pragma unroll
      for (int hs = 0; hs < 8; ++hs)
        st[jt] = __builtin_amdgcn_mfma_f32_32x32x16_bf16(ld16(qp + hs * 16), kb[hs], st[jt], 0, 0, 0);
    }

    // mask -> exp -> pack to PV A-frags (all in-register)
    bf16x8 pa[2][2];
    #pragma unroll
    for (int jt = 0; jt < 2; ++jt){
      unsigned bw = jt ? bw1 : bw0;
      float w[16];
      #pragma unroll
      for (int r = 0; r < 16; ++r){
        int jp = (r & 3) + 8 * (r >> 2) + 4 * h;
        float wv = ((bw >> jp) & 1u) ? __expf(st[jt][r]) : 0.f; // |s|<=1: exp safe
        w[r] = wv; dacc += wv;
      }
      unsigned x0 = cvtpk(w[0],  w[1]),  x1 = cvtpk(w[2],  w[3]);
      unsigned x2 = cvtpk(w[4],  w[5]),  x3 = cvtpk(w[6],  w[7]);
      unsigned x4 = cvtpk(w[8],  w[9]),  x5 = cvtpk(w[10], w[11]);
      unsigned x6 = cvtpk(w[12], w[13]), x7 = cvtpk(w[14], w[15]);
      unsigned za = __shfl_xor(h ? x0 : x2, 32);
      unsigned zb = __shfl_xor(h ? x1 : x3, 32);
      unsigned zc = __shfl_xor(h ? x4 : x6, 32);
      unsigned zd = __shfl_xor(h ? x5 : x7, 32);
      pa[jt][0] = h ? mk8(za, zb, x2, x3) : mk8(x0, x1, za, zb);
      pa[jt][1] = h ? mk8(zc, zd, x6, x7) : mk8(x4, x5, zc, zd);
    }

    __syncthreads();                        // ft(s) staged (barrier drains vmcnt)
    // PV: out[i=lc col][d] += P[i][j] * ft[j][d]
    #pragma unroll
    for (int ks = 0; ks < 4; ++ks){
      bf16x8 a = pa[ks >> 1][ks & 1];
      int up = ((jg * 8 + ks * 2 + h) ^ (lc & 15)) << 4;
      #pragma unroll
      for (int dt = 0; dt < 8; ++dt){
        int d = dt * 32 + lc;
        bf16x8 b = ld16(smem + d * 256 + up);
        pv[dt] = __builtin_amdgcn_mfma_f32_32x32x16_bf16(a, b, pv[dt], 0, 0, 0);
      }
    }
    if (s < 15){
      __syncthreads();                      // all PV(s) readers done
      stage(j0 + 128);                      // overlaps next QK^T
    }
  }

  // epilogue: merge jg pair via LDS, plain stores (no atomics)
  float dsum = dacc + __shfl_xor(dacc, 32);
  __syncthreads();
  float* red  = (float*)smem;               // [2 ig][32 i'][256 d]
  float* dred = (float*)(smem + 65536);     // [2 ig][32]
  if (jg == 0){
    #pragma unroll
    for (int dt = 0; dt < 8; ++dt)
      #pragma unroll
      for (int r = 0; r < 16; ++r){
        int ip = (r & 3) + 8 * (r >> 2) + 4 * h;
        red[ig * 8192 + ip * 256 + dt * 32 + lc] = pv[dt][r];
      }
    if (h == 0) dred[ig * 32 + lc] = dsum;
  }
  __syncthreads();
  if (jg == 1){
    float* np = num_p + (size_t)js * NN * DD;
    #pragma unroll
    for (int dt = 0; dt < 8; ++dt)
      #pragma unroll
      for (int r = 0; r < 16; ++r){
        int ip = (r & 3) + 8 * (r >> 2) + 4 * h;
        float v = pv[dt][r] + red[ig * 8192 + ip * 256 + dt * 32 + lc];
        np[(size_t)(i0 + ig * 32 + ip) * DD + dt * 32 + lc] = v;
      }
    if (h == 0) den_p[(size_t)js * NN + i0 + ig * 32 + lc] = dsum + dred[ig * 32 + lc];
  }
}

// ---------- finalize: sum 4 partials; out = den>0 ? 0.5*num/den + 0.5*f : f ----------
__global__ __launch_bounds__(256) void k_final(const float* __restrict__ num_p,
                                               const float* __restrict__ den_p,
                                               const float* __restrict__ f,
                                               float* __restrict__ out){
  int gid = blockIdx.x * 256 + threadIdx.x;
  int i = gid >> 6;
  f32x4 nv = (f32x4){0.f,0.f,0.f,0.f};
  float dv = 0.f;
  #pragma unroll
  for (int s = 0; s < 4; ++s){
    nv += *(const f32x4*)(num_p + (size_t)s * NN * DD + (size_t)gid * 4);
    dv += den_p[(size_t)s * NN + i];
  }
  f32x4 fv = *(const f32x4*)(f + (size_t)gid * 4);
  f32x4 o;
  if (dv > 0.f){
    float inv = 0.5f / dv;
    o = nv * inv + fv * 0.5f;
  } else {
    o = fv;
  }
  *(f32x4*)(out + (size_t)gid * 4) = o;
}

extern "C" void kernel_launch(void* const* d_in, const int* in_sizes, int n_in,
                              void* d_out, int out_size, void* d_ws, size_t ws_size,
                              hipStream_t stream){
  (void)in_sizes; (void)n_in; (void)out_size;
  const float* feat = (const float*)d_in[0];
  const int*   adj  = (const int*)d_in[1];
  const float* Wq   = (const float*)d_in[2];
  const float* Wk   = (const float*)d_in[3];
  float* out = (float*)d_out;
  char* ws = (char*)d_ws;
  unsigned short* Qn   = (unsigned short*)(ws);                 // 2MB
  unsigned short* Kn   = (unsigned short*)(ws + (2u << 20));    // 2MB
  unsigned short* ft   = (unsigned short*)(ws + (4u << 20));    // 4MB (pre-swizzled)
  unsigned*       bits = (unsigned*)(ws + (8u << 20));          // 8MB bitmask
  float*          num_p = (float*)(ws + (16u << 20));           // 4 x 8MB
  float*          den_p = (float*)(ws + (48u << 20));           // 4 x 32KB
  if (ws_size < (48u << 20) + 131072u) return;                  // ~48.13MB scratch

  k_transpose<<<dim3(128, 4), 256, 0, stream>>>(feat, ft);
  k_proj<<<128, 256, 0, stream>>>(feat, Wq, Wk, Qn, Kn);
  k_pack<<<4096, 256, 0, stream>>>(adj, bits);
  k_attn<<<512, 256, 0, stream>>>(bits, Qn, Kn, ft, num_p, den_p);
  k_final<<<2048, 256, 0, stream>>>(num_p, den_p, feat, out);
}

// Round 4
// 235.558 us; speedup vs baseline: 1.3593x; 1.3593x over previous
//
#include <hip/hip_runtime.h>
#include <stdint.h>
#include <stddef.h>

#define NN 8192
#define DD 256
#define HH 128

typedef short bf16x8  __attribute__((ext_vector_type(8)));
typedef float f32x4   __attribute__((ext_vector_type(4)));
typedef float f32x16  __attribute__((ext_vector_type(16)));
typedef int   i32x4   __attribute__((ext_vector_type(4)));

// f32 -> bf16 RNE
static __device__ __forceinline__ short f2bf(float x){
  unsigned u = __float_as_uint(x);
  u = (u + 0x7FFFu + ((u >> 16) & 1u)) >> 16;
  return (short)(unsigned short)u;
}
static __device__ __forceinline__ bf16x8 cvt8(const float* p){
  f32x4 a = *(const f32x4*)p;
  f32x4 b = *(const f32x4*)(p + 4);
  bf16x8 o;
  o[0]=f2bf(a[0]); o[1]=f2bf(a[1]); o[2]=f2bf(a[2]); o[3]=f2bf(a[3]);
  o[4]=f2bf(b[0]); o[5]=f2bf(b[1]); o[6]=f2bf(b[2]); o[7]=f2bf(b[3]);
  return o;
}
static __device__ __forceinline__ bf16x8 ld16(const void* p){
  i32x4 v = *(const i32x4*)p;
  return __builtin_bit_cast(bf16x8, v);
}

// ---------- features [N][D] f32 -> ft_frag: MFMA B-fragment-ready layout ----------
// frag (jt = j>>4, dt = d>>5): element (j,d) at ((jt*8+dt)*64 + lane)*8 + e,
// lane = (d&31) + 32*((j>>3)&1), e = j&7.  (B-frag: col=l&31, k=(l>>5)*8+e)
__global__ __launch_bounds__(256) void k_ftfrag(const float* __restrict__ f,
                                                unsigned short* __restrict__ ftf){
  int t = threadIdx.x;
  int fr = blockIdx.x * 4 + (t >> 6);   // frag id 0..4095
  int l  = t & 63;
  int jt = fr >> 3, dt = fr & 7;
  int j = jt * 16 + (l >> 5) * 8, d = dt * 32 + (l & 31);
  bf16x8 o;
  #pragma unroll
  for (int e = 0; e < 8; ++e) o[e] = f2bf(f[(size_t)(j + e) * DD + d]);
  *(bf16x8*)(ftf + (size_t)fr * 512 + l * 8) = o;
}

// ---------- projections ----------
// Kn: row-major [i][128] bf16 (read once into regs by k_attn).
// Qn: B-fragment-ready layout: element (j,k) at ((j>>5)*8 + (k>>4))*512
//     + ((j&31) + 32*((k>>3)&1))*8 + (k&7).
__global__ __launch_bounds__(256) void k_proj(const float* __restrict__ f,
                                              const float* __restrict__ Wq,
                                              const float* __restrict__ Wk,
                                              unsigned short* __restrict__ Qnf,
                                              unsigned short* __restrict__ Kn){
  int t = threadIdx.x, wave = t >> 6, l = t & 63;
  int i0 = blockIdx.x * 64 + wave * 16;
  int lr = l & 15, lk = l >> 4;
  bf16x8 ka[8];
  #pragma unroll
  for (int ks = 0; ks < 8; ++ks)
    ka[ks] = cvt8(f + (size_t)(i0 + lr) * DD + ks * 32 + lk * 8);
  for (int pj = 0; pj < 2; ++pj){
    const float* W = pj ? Wk : Wq;
    f32x4 acc[8];
    #pragma unroll
    for (int n = 0; n < 8; ++n) acc[n] = (f32x4){0.f,0.f,0.f,0.f};
    for (int ks = 0; ks < 8; ++ks)
      #pragma unroll
      for (int n = 0; n < 8; ++n){
        bf16x8 bb = cvt8(W + (size_t)(n * 16 + lr) * DD + ks * 32 + lk * 8);
        acc[n] = __builtin_amdgcn_mfma_f32_16x16x32_bf16(ka[ks], bb, acc[n], 0, 0, 0);
      }
    #pragma unroll
    for (int r = 0; r < 4; ++r){
      float n2 = 0.f;
      #pragma unroll
      for (int n = 0; n < 8; ++n){ float v = acc[n][r]; n2 += v * v; }
      n2 += __shfl_xor(n2, 1); n2 += __shfl_xor(n2, 2);
      n2 += __shfl_xor(n2, 4); n2 += __shfl_xor(n2, 8);
      float s = 1.f / fmaxf(sqrtf(n2), 1e-4f);   // torch cosine eps
      int row = i0 + lk * 4 + r;
      #pragma unroll
      for (int n = 0; n < 8; ++n){
        short v = f2bf(acc[n][r] * s);
        if (pj){
          Kn[(size_t)row * HH + n * 16 + lr] = (unsigned short)v;
        } else {
          size_t off = ((size_t)(row >> 5) * 8 + n) * 512
                     + ((row & 31) + 32 * (lr >> 3)) * 8 + (lr & 7);
          Qnf[off] = (unsigned short)v;
        }
      }
    }
  }
}

// ---------- fused masked-softmax attention (v4) ----------
// 512 blocks = 128 ib x 4 js (js = bid&3 -> XCD-pinned j-window).
// 4 waves: QK^T tile (ig = w>>1, jg = w&1) of S[64 i][64 j]; PV d-quarter wq = w.
// Non-swapped QK^T (S col = j = lane) -> adj loads coalesced.
// P via 8KB swizzled LDS; Qn/ft read as fragments straight from global (coalesced).
#define STEP(CUR, NXT, SS) {                                                      \
  const int j0 = jbase + (SS) * 64;                                               \
  const int jn = ((SS) < 31) ? j0 + 64 : j0;                                      \
  _Pragma("unroll")                                                               \
  for (int r = 0; r < 16; ++r)                                                    \
    NXT[r] = __builtin_nontemporal_load(                                          \
        adj + (size_t)(iA + (r & 3) + 8 * (r >> 2)) * NN + jn + jg * 32 + lc);    \
  f32x16 st;                                                                      \
  _Pragma("unroll") for (int e = 0; e < 16; ++e) st[e] = 0.f;                     \
  { const unsigned short* qb = Qnf + ((size_t)((j0 + jg * 32) >> 5) * 8) * 512 + (size_t)l * 8; \
    _Pragma("unroll")                                                             \
    for (int hs = 0; hs < 8; ++hs)                                                \
      st = __builtin_amdgcn_mfma_f32_32x32x16_bf16(kb[hs], ld16(qb + hs * 512), st, 0, 0, 0); } \
  bf16x8 bv[8];                                                                   \
  { const unsigned short* fb = ftf + ((size_t)(j0 >> 4) * 8 + wq * 2) * 512 + (size_t)l * 8; \
    _Pragma("unroll")                                                             \
    for (int ks = 0; ks < 4; ++ks){                                               \
      bv[ks * 2]     = ld16(fb + ks * 4096);                                      \
      bv[ks * 2 + 1] = ld16(fb + ks * 4096 + 512); } }                            \
  _Pragma("unroll")                                                               \
  for (int r = 0; r < 16; ++r){                                                   \
    float wv = (CUR[r] > 0) ? __expf(st[r]) : 0.f;  /* |s|<=1: exp safe */        \
    dacc[r] += wv;                                                                \
    int row = ig * 32 + (r & 3) + 8 * (r >> 2) + 4 * h;                           \
    int byo = row * 128 + (((jg * 32 + lc) * 2) ^ ((row & 7) << 4));              \
    *(unsigned short*)(p_lds + byo) = (unsigned short)f2bf(wv);                   \
  }                                                                               \
  __syncthreads();                                                                \
  _Pragma("unroll")                                                               \
  for (int ks = 0; ks < 4; ++ks){                                                 \
    int ko = (ks * 32 + h * 16) ^ ((lc & 7) << 4);                                \
    bf16x8 pa0 = ld16(p_lds + lc * 128 + ko);                                     \
    bf16x8 pa1 = ld16(p_lds + (32 + lc) * 128 + ko);                              \
    pv00 = __builtin_amdgcn_mfma_f32_32x32x16_bf16(pa0, bv[ks*2],   pv00, 0,0,0); \
    pv01 = __builtin_amdgcn_mfma_f32_32x32x16_bf16(pa0, bv[ks*2+1], pv01, 0,0,0); \
    pv10 = __builtin_amdgcn_mfma_f32_32x32x16_bf16(pa1, bv[ks*2],   pv10, 0,0,0); \
    pv11 = __builtin_amdgcn_mfma_f32_32x32x16_bf16(pa1, bv[ks*2+1], pv11, 0,0,0); \
  }                                                                               \
  __syncthreads();                                                                \
}

__global__ __launch_bounds__(256, 2) void k_attn(
      const int* __restrict__ adj,
      const unsigned short* __restrict__ Qnf, const unsigned short* __restrict__ Kn,
      const unsigned short* __restrict__ ftf,
      float* __restrict__ num_p, float* __restrict__ den_p){
  __shared__ __attribute__((aligned(16))) char p_lds[8192];  // P [64 i][64 j] bf16, XOR-swizzled
  int t = threadIdx.x, wave = t >> 6, l = t & 63;
  int lc = l & 31, h = l >> 5;
  int ig = wave >> 1, jg = wave & 1, wq = wave;
  int ib = blockIdx.x >> 2, js = blockIdx.x & 3;   // js = (bid&3): XCD-pinned j-window
  int i0 = ib * 64;
  int jbase = js * 2048;
  int iA = i0 + ig * 32 + 4 * h;

  // Kn A-frags: lane holds Kn[i0+ig*32+lc][hs*16 + h*8 + e]  (once, ~scattered, negligible)
  bf16x8 kb[8];
  { const unsigned short* kp = Kn + (size_t)(i0 + ig * 32 + lc) * HH + h * 8;
    #pragma unroll
    for (int hs = 0; hs < 8; ++hs) kb[hs] = ld16(kp + hs * 16); }

  f32x16 pv00, pv01, pv10, pv11;
  #pragma unroll
  for (int e = 0; e < 16; ++e){ pv00[e]=0.f; pv01[e]=0.f; pv10[e]=0.f; pv11[e]=0.f; }
  float dacc[16];
  #pragma unroll
  for (int r = 0; r < 16; ++r) dacc[r] = 0.f;

  int adjA[16], adjB[16];
  #pragma unroll
  for (int r = 0; r < 16; ++r)
    adjA[r] = __builtin_nontemporal_load(
        adj + (size_t)(iA + (r & 3) + 8 * (r >> 2)) * NN + jbase + jg * 32 + lc);

  for (int sp = 0; sp < 16; ++sp){
    STEP(adjA, adjB, 2 * sp)
    STEP(adjB, adjA, 2 * sp + 1)
  }

  // den partials: reduce over j-lanes (within h-half), store per (js,jg)
  #pragma unroll
  for (int r = 0; r < 16; ++r){
    float v = dacc[r];
    v += __shfl_xor(v, 1); v += __shfl_xor(v, 2); v += __shfl_xor(v, 4);
    v += __shfl_xor(v, 8); v += __shfl_xor(v, 16);
    if (lc == 0){
      int i = i0 + ig * 32 + (r & 3) + 8 * (r >> 2) + 4 * h;
      den_p[(size_t)(js * 2 + jg) * NN + i] = v;
    }
  }
  // num partials: plain coalesced stores
  float* np = num_p + (size_t)js * NN * DD;
  #pragma unroll
  for (int r = 0; r < 16; ++r){
    int i = i0 + (r & 3) + 8 * (r >> 2) + 4 * h;
    int d = wq * 64 + lc;
    np[(size_t)i * DD + d]             = pv00[r];
    np[(size_t)i * DD + d + 32]        = pv01[r];
    np[(size_t)(i + 32) * DD + d]      = pv10[r];
    np[(size_t)(i + 32) * DD + d + 32] = pv11[r];
  }
}

// ---------- finalize: sum partials; out = den>0 ? 0.5*num/den + 0.5*f : f ----------
__global__ __launch_bounds__(256) void k_final(const float* __restrict__ num_p,
                                               const float* __restrict__ den_p,
                                               const float* __restrict__ f,
                                               float* __restrict__ out){
  int gid = blockIdx.x * 256 + threadIdx.x;
  int i = gid >> 6;
  f32x4 nv = (f32x4){0.f,0.f,0.f,0.f};
  float dv = 0.f;
  #pragma unroll
  for (int s = 0; s < 4; ++s)
    nv += *(const f32x4*)(num_p + (size_t)s * NN * DD + (size_t)gid * 4);
  #pragma unroll
  for (int s = 0; s < 8; ++s)
    dv += den_p[(size_t)s * NN + i];
  f32x4 fv = *(const f32x4*)(f + (size_t)gid * 4);
  f32x4 o;
  if (dv > 0.f){
    float inv = 0.5f / dv;
    o = nv * inv + fv * 0.5f;
  } else {
    o = fv;   // no-neighbor row keeps features
  }
  *(f32x4*)(out + (size_t)gid * 4) = o;
}

extern "C" void kernel_launch(void* const* d_in, const int* in_sizes, int n_in,
                              void* d_out, int out_size, void* d_ws, size_t ws_size,
                              hipStream_t stream){
  (void)in_sizes; (void)n_in; (void)out_size;
  const float* feat = (const float*)d_in[0];
  const int*   adj  = (const int*)d_in[1];
  const float* Wq   = (const float*)d_in[2];
  const float* Wk   = (const float*)d_in[3];
  float* out = (float*)d_out;
  char* ws = (char*)d_ws;
  unsigned short* Qnf  = (unsigned short*)(ws);                 // 2MB frag-layout
  unsigned short* Kn   = (unsigned short*)(ws + (2u << 20));    // 2MB row-major
  unsigned short* ftf  = (unsigned short*)(ws + (4u << 20));    // 4MB frag-layout
  float*          num_p = (float*)(ws + (8u << 20));            // 4 x 8MB
  float*          den_p = (float*)(ws + (40u << 20));           // 8 x 32KB
  if (ws_size < (40u << 20) + 262144u) return;                  // ~40.25MB scratch

  k_ftfrag<<<1024, 256, 0, stream>>>(feat, ftf);
  k_proj<<<128, 256, 0, stream>>>(feat, Wq, Wk, Qnf, Kn);
  k_attn<<<512, 256, 0, stream>>>(adj, Qnf, Kn, ftf, num_p, den_p);
  k_final<<<2048, 256, 0, stream>>>(num_p, den_p, feat, out);
}

// Round 5
// 219.866 us; speedup vs baseline: 1.4564x; 1.0714x over previous
//
#include <hip/hip_runtime.h>
#include <stdint.h>
#include <stddef.h>

#define NN 8192
#define DD 256
#define HH 128

typedef short bf16x8  __attribute__((ext_vector_type(8)));
typedef float f32x4   __attribute__((ext_vector_type(4)));
typedef float f32x16  __attribute__((ext_vector_type(16)));
typedef int   i32x4   __attribute__((ext_vector_type(4)));

// f32 -> bf16 RNE
static __device__ __forceinline__ short f2bf(float x){
  unsigned u = __float_as_uint(x);
  u = (u + 0x7FFFu + ((u >> 16) & 1u)) >> 16;
  return (short)(unsigned short)u;
}
static __device__ __forceinline__ bf16x8 cvt8(const float* p){
  f32x4 a = *(const f32x4*)p;
  f32x4 b = *(const f32x4*)(p + 4);
  bf16x8 o;
  o[0]=f2bf(a[0]); o[1]=f2bf(a[1]); o[2]=f2bf(a[2]); o[3]=f2bf(a[3]);
  o[4]=f2bf(b[0]); o[5]=f2bf(b[1]); o[6]=f2bf(b[2]); o[7]=f2bf(b[3]);
  return o;
}
static __device__ __forceinline__ bf16x8 ld16(const void* p){
  i32x4 v = *(const i32x4*)p;
  return __builtin_bit_cast(bf16x8, v);
}

// ---------- features [N][D] f32 -> ft_frag: MFMA B-fragment-ready layout ----------
__global__ __launch_bounds__(256) void k_ftfrag(const float* __restrict__ f,
                                                unsigned short* __restrict__ ftf){
  int t = threadIdx.x;
  int fr = blockIdx.x * 4 + (t >> 6);   // frag id 0..4095
  int l  = t & 63;
  int jt = fr >> 3, dt = fr & 7;
  int j = jt * 16 + (l >> 5) * 8, d = dt * 32 + (l & 31);
  bf16x8 o;
  #pragma unroll
  for (int e = 0; e < 8; ++e) o[e] = f2bf(f[(size_t)(j + e) * DD + d]);
  *(bf16x8*)(ftf + (size_t)fr * 512 + l * 8) = o;
}

// ---------- projections ----------
// Kn: row-major [i][128] bf16. Qn: B-fragment-ready (see k_attn).
__global__ __launch_bounds__(256) void k_proj(const float* __restrict__ f,
                                              const float* __restrict__ Wq,
                                              const float* __restrict__ Wk,
                                              unsigned short* __restrict__ Qnf,
                                              unsigned short* __restrict__ Kn){
  int t = threadIdx.x, wave = t >> 6, l = t & 63;
  int i0 = blockIdx.x * 64 + wave * 16;
  int lr = l & 15, lk = l >> 4;
  bf16x8 ka[8];
  #pragma unroll
  for (int ks = 0; ks < 8; ++ks)
    ka[ks] = cvt8(f + (size_t)(i0 + lr) * DD + ks * 32 + lk * 8);
  for (int pj = 0; pj < 2; ++pj){
    const float* W = pj ? Wk : Wq;
    f32x4 acc[8];
    #pragma unroll
    for (int n = 0; n < 8; ++n) acc[n] = (f32x4){0.f,0.f,0.f,0.f};
    for (int ks = 0; ks < 8; ++ks)
      #pragma unroll
      for (int n = 0; n < 8; ++n){
        bf16x8 bb = cvt8(W + (size_t)(n * 16 + lr) * DD + ks * 32 + lk * 8);
        acc[n] = __builtin_amdgcn_mfma_f32_16x16x32_bf16(ka[ks], bb, acc[n], 0, 0, 0);
      }
    #pragma unroll
    for (int r = 0; r < 4; ++r){
      float n2 = 0.f;
      #pragma unroll
      for (int n = 0; n < 8; ++n){ float v = acc[n][r]; n2 += v * v; }
      n2 += __shfl_xor(n2, 1); n2 += __shfl_xor(n2, 2);
      n2 += __shfl_xor(n2, 4); n2 += __shfl_xor(n2, 8);
      float s = 1.f / fmaxf(sqrtf(n2), 1e-4f);   // torch cosine eps
      int row = i0 + lk * 4 + r;
      #pragma unroll
      for (int n = 0; n < 8; ++n){
        short v = f2bf(acc[n][r] * s);
        if (pj){
          Kn[(size_t)row * HH + n * 16 + lr] = (unsigned short)v;
        } else {
          size_t off = ((size_t)(row >> 5) * 8 + n) * 512
                     + ((row & 31) + 32 * (lr >> 3)) * 8 + (lr & 7);
          Qnf[off] = (unsigned short)v;
        }
      }
    }
  }
}

// ---------- fused masked-softmax attention (v5) ----------
// 512 blocks = 128 ib x 4 js. 4 waves. Per 64-j step:
//  adj 64x64 tile COALESCED (4 rows x 256B per dwordx4) double-buffered in LDS;
//  QK^T (32x32x16, frag loads from global/L2) -> exp via LDS mask -> P via 8KB
//  swizzled LDS -> PV. adj read exactly once at streaming BW.
__global__ __launch_bounds__(256, 2) void k_attn(
      const int* __restrict__ adj,
      const unsigned short* __restrict__ Qnf, const unsigned short* __restrict__ Kn,
      const unsigned short* __restrict__ ftf,
      float* __restrict__ num_p, float* __restrict__ den_p){
  __shared__ __attribute__((aligned(16))) char p_lds[8192];     // P [64i][64j] bf16 swizzled
  __shared__ __attribute__((aligned(16))) int adj_lds[2][64][64]; // raw adj tiles, dbuf
  int t = threadIdx.x, wave = t >> 6, l = t & 63;
  int lc = l & 31, h = l >> 5;
  int ig = wave >> 1, jg = wave & 1, wq = wave;
  int ib = blockIdx.x >> 2, js = blockIdx.x & 3;
  int i0 = ib * 64;
  int jbase = js * 2048;

  // Kn A-frags: lane holds Kn[i0+ig*32+lc][hs*16 + h*8 + e]
  bf16x8 kb[8];
  { const unsigned short* kp = Kn + (size_t)(i0 + ig * 32 + lc) * HH + h * 8;
    #pragma unroll
    for (int hs = 0; hs < 8; ++hs) kb[hs] = ld16(kp + hs * 16); }

  f32x16 pv00, pv01, pv10, pv11;
  #pragma unroll
  for (int e = 0; e < 16; ++e){ pv00[e]=0.f; pv01[e]=0.f; pv10[e]=0.f; pv11[e]=0.f; }
  float dacc[16];
  #pragma unroll
  for (int r = 0; r < 16; ++r) dacc[r] = 0.f;

  // adj tile rows for this wave: wave*16 + k4*4 + (l>>4); cols (l&15)*4 (dwordx4)
  int arow = wave * 16 + (l >> 4);
  int acol = (l & 15) * 4;

  // prologue: stage adj step-0 tile (coalesced)
  #pragma unroll
  for (int k4 = 0; k4 < 4; ++k4){
    i32x4 v = __builtin_nontemporal_load(
        (const i32x4*)(adj + (size_t)(i0 + arow + k4 * 4) * NN + jbase + acol));
    *(i32x4*)&adj_lds[0][arow + k4 * 4][acol] = v;
  }
  __syncthreads();

  for (int s = 0; s < 32; ++s){
    int j0 = jbase + s * 64;
    int cur = s & 1, nxt = cur ^ 1;

    // issue Qn frag loads (consumed by QK)
    bf16x8 qv[8];
    { const unsigned short* qb = Qnf + ((size_t)((j0 + jg * 32) >> 5) * 8) * 512 + (size_t)l * 8;
      #pragma unroll
      for (int hs = 0; hs < 8; ++hs) qv[hs] = ld16(qb + hs * 512); }

    // issue adj prefetch for s+1 (coalesced, consumed post-barrier1)
    i32x4 av[4];
    if (s < 31){
      #pragma unroll
      for (int k4 = 0; k4 < 4; ++k4)
        av[k4] = __builtin_nontemporal_load(
            (const i32x4*)(adj + (size_t)(i0 + arow + k4 * 4) * NN + j0 + 64 + acol));
    }

    // issue ft frag loads (consumed by PV)
    bf16x8 bv[8];
    { const unsigned short* fb = ftf + ((size_t)(j0 >> 4) * 8 + wq * 2) * 512 + (size_t)l * 8;
      #pragma unroll
      for (int ks = 0; ks < 4; ++ks){
        bv[ks * 2]     = ld16(fb + ks * 4096);
        bv[ks * 2 + 1] = ld16(fb + ks * 4096 + 512); } }

    // QK^T: st[r] = S[i0+ig*32 + (r&3)+8*(r>>2)+4h][j0 + jg*32 + lc]
    f32x16 st;
    #pragma unroll
    for (int e = 0; e < 16; ++e) st[e] = 0.f;
    #pragma unroll
    for (int hs = 0; hs < 8; ++hs)
      st = __builtin_amdgcn_mfma_f32_32x32x16_bf16(kb[hs], qv[hs], st, 0, 0, 0);

    // mask (from LDS) -> exp -> P to swizzled LDS
    #pragma unroll
    for (int r = 0; r < 16; ++r){
      int row = ig * 32 + (r & 3) + 8 * (r >> 2) + 4 * h;
      int a = adj_lds[cur][row][jg * 32 + lc];
      float wv = (a > 0) ? __expf(st[r]) : 0.f;   // |s|<=1: exp safe, no max needed
      dacc[r] += wv;
      int byo = row * 128 + (((jg * 32 + lc) * 2) ^ ((row & 7) << 4));
      *(unsigned short*)(p_lds + byo) = (unsigned short)f2bf(wv);
    }
    __syncthreads();                     // barrier1: P visible (drains av too)

    // write prefetched adj tile to other buffer
    if (s < 31){
      #pragma unroll
      for (int k4 = 0; k4 < 4; ++k4)
        *(i32x4*)&adj_lds[nxt][arow + k4 * 4][acol] = av[k4];
    }

    // PV: pvXY += P(full 64j) * ft(d-quarter wq)
    #pragma unroll
    for (int ks = 0; ks < 4; ++ks){
      int ko = (ks * 32 + h * 16) ^ ((lc & 7) << 4);
      bf16x8 pa0 = ld16(p_lds + lc * 128 + ko);
      bf16x8 pa1 = ld16(p_lds + (32 + lc) * 128 + ko);
      pv00 = __builtin_amdgcn_mfma_f32_32x32x16_bf16(pa0, bv[ks*2],   pv00, 0,0,0);
      pv01 = __builtin_amdgcn_mfma_f32_32x32x16_bf16(pa0, bv[ks*2+1], pv01, 0,0,0);
      pv10 = __builtin_amdgcn_mfma_f32_32x32x16_bf16(pa1, bv[ks*2],   pv10, 0,0,0);
      pv11 = __builtin_amdgcn_mfma_f32_32x32x16_bf16(pa1, bv[ks*2+1], pv11, 0,0,0);
    }
    __syncthreads();                     // barrier2: PV done; adj_lds[nxt] visible
  }

  // den partials: reduce over j-lanes, store per (js,jg)
  #pragma unroll
  for (int r = 0; r < 16; ++r){
    float v = dacc[r];
    v += __shfl_xor(v, 1); v += __shfl_xor(v, 2); v += __shfl_xor(v, 4);
    v += __shfl_xor(v, 8); v += __shfl_xor(v, 16);
    if (lc == 0){
      int i = i0 + ig * 32 + (r & 3) + 8 * (r >> 2) + 4 * h;
      den_p[(size_t)(js * 2 + jg) * NN + i] = v;
    }
  }
  // num partials: plain coalesced stores (per-js region)
  float* np = num_p + (size_t)js * NN * DD;
  #pragma unroll
  for (int r = 0; r < 16; ++r){
    int i = i0 + (r & 3) + 8 * (r >> 2) + 4 * h;
    int d = wq * 64 + lc;
    np[(size_t)i * DD + d]             = pv00[r];
    np[(size_t)i * DD + d + 32]        = pv01[r];
    np[(size_t)(i + 32) * DD + d]      = pv10[r];
    np[(size_t)(i + 32) * DD + d + 32] = pv11[r];
  }
}

// ---------- finalize: sum partials; out = den>0 ? 0.5*num/den + 0.5*f : f ----------
__global__ __launch_bounds__(256) void k_final(const float* __restrict__ num_p,
                                               const float* __restrict__ den_p,
                                               const float* __restrict__ f,
                                               float* __restrict__ out){
  int gid = blockIdx.x * 256 + threadIdx.x;
  int i = gid >> 6;
  f32x4 nv = (f32x4){0.f,0.f,0.f,0.f};
  float dv = 0.f;
  #pragma unroll
  for (int s = 0; s < 4; ++s)
    nv += *(const f32x4*)(num_p + (size_t)s * NN * DD + (size_t)gid * 4);
  #pragma unroll
  for (int s = 0; s < 8; ++s)
    dv += den_p[(size_t)s * NN + i];
  f32x4 fv = *(const f32x4*)(f + (size_t)gid * 4);
  f32x4 o;
  if (dv > 0.f){
    float inv = 0.5f / dv;
    o = nv * inv + fv * 0.5f;
  } else {
    o = fv;   // no-neighbor row keeps features
  }
  *(f32x4*)(out + (size_t)gid * 4) = o;
}

extern "C" void kernel_launch(void* const* d_in, const int* in_sizes, int n_in,
                              void* d_out, int out_size, void* d_ws, size_t ws_size,
                              hipStream_t stream){
  (void)in_sizes; (void)n_in; (void)out_size;
  const float* feat = (const float*)d_in[0];
  const int*   adj  = (const int*)d_in[1];
  const float* Wq   = (const float*)d_in[2];
  const float* Wk   = (const float*)d_in[3];
  float* out = (float*)d_out;
  char* ws = (char*)d_ws;
  unsigned short* Qnf  = (unsigned short*)(ws);                 // 2MB frag-layout
  unsigned short* Kn   = (unsigned short*)(ws + (2u << 20));    // 2MB row-major
  unsigned short* ftf  = (unsigned short*)(ws + (4u << 20));    // 4MB frag-layout
  float*          num_p = (float*)(ws + (8u << 20));            // 4 x 8MB
  float*          den_p = (float*)(ws + (40u << 20));           // 8 x 32KB
  if (ws_size < (40u << 20) + 262144u) return;                  // ~40.25MB scratch

  k_ftfrag<<<1024, 256, 0, stream>>>(feat, ftf);
  k_proj<<<128, 256, 0, stream>>>(feat, Wq, Wk, Qnf, Kn);
  k_attn<<<512, 256, 0, stream>>>(adj, Qnf, Kn, ftf, num_p, den_p);
  k_final<<<2048, 256, 0, stream>>>(num_p, den_p, feat, out);
}